// Round 1
// baseline (1571.742 us; speedup 1.0000x reference)
//
#include <hip/hip_runtime.h>
#include <math.h>

#define B_ 4
#define S_ 2048
#define D_ 512
#define H_ 8
#define NEG_FILL (-1e-9f)

// ---------------------------------------------------------------------------
// Kernel 1: QKV projection.  X[8192x512] @ W[512x512] -> head layout [B,H,S,64]
// tile 64x64, K-step 16, 256 threads, 4x4 micro-tile per thread.
// ---------------------------------------------------------------------------
__global__ __launch_bounds__(256) void qkv_gemm(
    const float* __restrict__ q, const float* __restrict__ k, const float* __restrict__ v,
    const float* __restrict__ Wq, const float* __restrict__ Wk, const float* __restrict__ Wv,
    float* __restrict__ qh, float* __restrict__ kh, float* __restrict__ vh)
{
  const float* X; const float* W; float* Y;
  int z = blockIdx.z;
  if (z == 0)      { X = q; W = Wq; Y = qh; }
  else if (z == 1) { X = k; W = Wk; Y = kh; }
  else             { X = v; W = Wv; Y = vh; }

  __shared__ float Xs[16][72];   // [k][m], transposed, padded
  __shared__ float Ws[16][72];   // [k][n], padded

  const int t  = threadIdx.x;
  const int tx = t & 15, ty = t >> 4;
  const int tile_n = blockIdx.x * 64;
  const int tile_m = blockIdx.y * 64;

  const int lr = t >> 2;          // 0..63 (row within tile for X load)
  const int lk = (t & 3) * 4;     // 0,4,8,12
  const int wk = t >> 4;          // 0..15
  const int wn = (t & 15) * 4;    // 0..60

  float acc[4][4] = {};

  for (int k0 = 0; k0 < 512; k0 += 16) {
    float4 xv = *(const float4*)&X[(size_t)(tile_m + lr) * 512 + k0 + lk];
    Xs[lk+0][lr] = xv.x; Xs[lk+1][lr] = xv.y; Xs[lk+2][lr] = xv.z; Xs[lk+3][lr] = xv.w;
    float4 wv = *(const float4*)&W[(size_t)(k0 + wk) * 512 + tile_n + wn];
    *(float4*)&Ws[wk][wn] = wv;
    __syncthreads();
    #pragma unroll
    for (int kk = 0; kk < 16; ++kk) {
      float4 af = *(const float4*)&Xs[kk][ty*4];
      float4 bf = *(const float4*)&Ws[kk][tx*4];
      float a[4] = {af.x, af.y, af.z, af.w};
      float b[4] = {bf.x, bf.y, bf.z, bf.w};
      #pragma unroll
      for (int i = 0; i < 4; ++i)
        #pragma unroll
        for (int j = 0; j < 4; ++j)
          acc[i][j] = fmaf(a[i], b[j], acc[i][j]);
    }
    __syncthreads();
  }

  // write to head layout: col c = tile_n + tx*4 + j ; h = tile_n/64 (tile-uniform)
  const int h  = tile_n >> 6;
  const int dd = tx * 4;
  #pragma unroll
  for (int i = 0; i < 4; ++i) {
    int r = tile_m + ty * 4 + i;
    int b = r >> 11, s = r & (S_ - 1);
    float4 o = make_float4(acc[i][0], acc[i][1], acc[i][2], acc[i][3]);
    *(float4*)&Y[(((size_t)(b * H_ + h) * S_) + s) * 64 + dd] = o;
  }
}

// ---------------------------------------------------------------------------
// Kernel 2: fused attention.  One block per (b,h, 64-row q tile).
// Phase A: online row max/sum over all keys (scores recomputed, not stored).
// Phase B: recompute scores, p = exp(s-m)/l, write attn (coalesced via LDS),
//          accumulate O = P @ V in registers.
// ---------------------------------------------------------------------------
__device__ __forceinline__ void compute_sc(const float* __restrict__ qt,
                                           const float* __restrict__ ktl,
                                           int tx, int ty, float sc[4][4])
{
  #pragma unroll
  for (int i = 0; i < 4; ++i)
    #pragma unroll
    for (int j = 0; j < 4; ++j) sc[i][j] = 0.f;
  #pragma unroll 8
  for (int d = 0; d < 64; ++d) {
    float4 af = *(const float4*)&qt[d * 68 + ty * 4];
    float4 bf = *(const float4*)&ktl[d * 68 + tx * 4];
    float a[4] = {af.x, af.y, af.z, af.w};
    float b[4] = {bf.x, bf.y, bf.z, bf.w};
    #pragma unroll
    for (int i = 0; i < 4; ++i)
      #pragma unroll
      for (int j = 0; j < 4; ++j)
        sc[i][j] = fmaf(a[i], b[j], sc[i][j]);
  }
}

__global__ __launch_bounds__(256) void attn_kernel(
    const float* __restrict__ qh, const float* __restrict__ kh, const float* __restrict__ vh,
    const int* __restrict__ src_mask,
    float* __restrict__ attn_out, float* __restrict__ oh)
{
  const int t  = threadIdx.x;
  const int tx = t & 15, ty = t >> 4;
  const int bh = blockIdx.y;
  const int b  = bh >> 3;          // H_=8
  const int h  = bh & 7;
  const int q0 = blockIdx.x * 64;

  __shared__ float sbuf[3 * 64 * 68];          // 52224 B
  float* qt  = sbuf;                 // [64 d][68] q transposed (d-major)
  float* ktl = sbuf + 64 * 68;       // [64 d][68] k transposed; aliased as p[64 r][68]
  float* vsr = sbuf + 2 * 64 * 68;   // phase B: v [64 kc][68]; phase A tail: red arrays
  __shared__ int   smq[64];
  __shared__ int   smk[64];
  __shared__ float rowm_s[64];
  __shared__ float rowinv_s[64];

  const float* qg = qh + ((size_t)bh * S_ + q0) * 64;
  const float* kg = kh + (size_t)bh * S_ * 64;
  const float* vg = vh + (size_t)bh * S_ * 64;

  // stage q tile transposed (once)
  #pragma unroll
  for (int rep = 0; rep < 4; ++rep) {
    int f   = rep * 256 + t;         // float4 index 0..1023
    int row = f >> 4;
    int d0  = (f & 15) * 4;
    float4 x = *(const float4*)&qg[(size_t)row * 64 + d0];
    qt[(d0+0)*68 + row] = x.x;
    qt[(d0+1)*68 + row] = x.y;
    qt[(d0+2)*68 + row] = x.z;
    qt[(d0+3)*68 + row] = x.w;
  }
  if (t < 64) smq[t] = src_mask[b * S_ + q0 + t];

  float mrow[4], lrow[4];
  #pragma unroll
  for (int i = 0; i < 4; ++i) { mrow[i] = -INFINITY; lrow[i] = 0.f; }

  // ---------------- Phase A: row max & sum ----------------
  for (int kt0 = 0; kt0 < S_; kt0 += 64) {
    __syncthreads();               // guard ktl overwrite vs prior-iter readers
    #pragma unroll
    for (int rep = 0; rep < 4; ++rep) {
      int f   = rep * 256 + t;
      int row = f >> 4;
      int d0  = (f & 15) * 4;
      float4 x = *(const float4*)&kg[(size_t)(kt0 + row) * 64 + d0];
      ktl[(d0+0)*68 + row] = x.x;
      ktl[(d0+1)*68 + row] = x.y;
      ktl[(d0+2)*68 + row] = x.z;
      ktl[(d0+3)*68 + row] = x.w;
    }
    if (t < 64) smk[t] = src_mask[b * S_ + kt0 + t];
    __syncthreads();

    float sc[4][4];
    compute_sc(qt, ktl, tx, ty, sc);

    #pragma unroll
    for (int i = 0; i < 4; ++i) {
      int  qi = q0 + ty * 4 + i;
      int  mq = smq[ty * 4 + i];
      float s[4];
      #pragma unroll
      for (int j = 0; j < 4; ++j) {
        int kj = kt0 + tx * 4 + j;
        float ss = sc[i][j] * 0.125f;
        if (!((mq && smk[tx * 4 + j]) || (qi == kj))) ss = NEG_FILL;
        s[j] = ss;
      }
      float mx = fmaxf(fmaxf(s[0], s[1]), fmaxf(s[2], s[3]));
      float mnew = fmaxf(mrow[i], mx);
      float l = lrow[i] * __expf(mrow[i] - mnew);
      #pragma unroll
      for (int j = 0; j < 4; ++j) l += __expf(s[j] - mnew);
      mrow[i] = mnew; lrow[i] = l;
    }
  }

  // reduce (m,l) across the 16 tx-threads per row (red arrays live in vsr)
  float* redm = vsr;               // [64][16]
  float* redl = vsr + 1024;        // [64][16]
  __syncthreads();
  #pragma unroll
  for (int i = 0; i < 4; ++i) {
    redm[(ty * 4 + i) * 16 + tx] = mrow[i];
    redl[(ty * 4 + i) * 16 + tx] = lrow[i];
  }
  __syncthreads();
  if (t < 64) {
    float m = -INFINITY;
    for (int x = 0; x < 16; ++x) m = fmaxf(m, redm[t * 16 + x]);
    float l = 0.f;
    for (int x = 0; x < 16; ++x) l += redl[t * 16 + x] * __expf(redm[t * 16 + x] - m);
    rowm_s[t]   = m;
    rowinv_s[t] = 1.f / l;
  }

  float oacc[4][4] = {};

  // ---------------- Phase B: attn write + PV ----------------
  for (int kt0 = 0; kt0 < S_; kt0 += 64) {
    __syncthreads();   // rowm_s visible; guard ktl/vsr overwrite vs prior readers
    #pragma unroll
    for (int rep = 0; rep < 4; ++rep) {
      int f   = rep * 256 + t;
      int row = f >> 4;
      int d0  = (f & 15) * 4;
      float4 x = *(const float4*)&kg[(size_t)(kt0 + row) * 64 + d0];
      ktl[(d0+0)*68 + row] = x.x;
      ktl[(d0+1)*68 + row] = x.y;
      ktl[(d0+2)*68 + row] = x.z;
      ktl[(d0+3)*68 + row] = x.w;
      float4 y = *(const float4*)&vg[(size_t)(kt0 + row) * 64 + d0];
      *(float4*)&vsr[row * 68 + d0] = y;
    }
    if (t < 64) smk[t] = src_mask[b * S_ + kt0 + t];
    __syncthreads();

    float sc[4][4];
    compute_sc(qt, ktl, tx, ty, sc);

    float p[4][4];
    #pragma unroll
    for (int i = 0; i < 4; ++i) {
      int   qi  = q0 + ty * 4 + i;
      int   mq  = smq[ty * 4 + i];
      float m   = rowm_s[ty * 4 + i];
      float inv = rowinv_s[ty * 4 + i];
      #pragma unroll
      for (int j = 0; j < 4; ++j) {
        int kj = kt0 + tx * 4 + j;
        float ss = sc[i][j] * 0.125f;
        if (!((mq && smk[tx * 4 + j]) || (qi == kj))) ss = NEG_FILL;
        p[i][j] = __expf(ss - m) * inv;
      }
    }

    __syncthreads();               // all score reads of ktl done before aliasing
    float* pb = ktl;               // reuse ktl as p tile [64 r][68]
    #pragma unroll
    for (int i = 0; i < 4; ++i)
      #pragma unroll
      for (int j = 0; j < 4; ++j)
        pb[(ty * 4 + i) * 68 + tx * 4 + j] = p[i][j];
    __syncthreads();

    // coalesced attn write: thread t -> row t/4, 16 consecutive floats
    {
      int row = t >> 2;
      int c0  = (t & 3) * 16;
      size_t base = ((size_t)bh * S_ + (q0 + row)) * S_ + kt0 + c0;
      #pragma unroll
      for (int u = 0; u < 4; ++u) {
        float4 x = *(const float4*)&pb[row * 68 + c0 + u * 4];
        *(float4*)&attn_out[base + u * 4] = x;
      }
    }

    // PV accumulate: oacc[i][j] += p[r_i][kc] * v[kc][d_j]
    #pragma unroll 4
    for (int kc = 0; kc < 64; ++kc) {
      float4 vf = *(const float4*)&vsr[kc * 68 + tx * 4];
      float vv[4] = {vf.x, vf.y, vf.z, vf.w};
      #pragma unroll
      for (int i = 0; i < 4; ++i) {
        float pv = pb[(ty * 4 + i) * 68 + kc];
        #pragma unroll
        for (int j = 0; j < 4; ++j)
          oacc[i][j] = fmaf(pv, vv[j], oacc[i][j]);
      }
    }
  }

  // write O tile to oh [B*S, 512] at cols h*64 + tx*4
  #pragma unroll
  for (int i = 0; i < 4; ++i) {
    size_t off = ((size_t)b * S_ + q0 + ty * 4 + i) * 512 + h * 64 + tx * 4;
    *(float4*)&oh[off] = make_float4(oacc[i][0], oacc[i][1], oacc[i][2], oacc[i][3]);
  }
}

// ---------------------------------------------------------------------------
// Kernel 3: out = oh @ Wo + residual(q)   -> d_out[0 .. 4M) row-major
// ---------------------------------------------------------------------------
__global__ __launch_bounds__(256) void out_gemm(
    const float* __restrict__ X, const float* __restrict__ Wo,
    const float* __restrict__ resid, float* __restrict__ Y)
{
  __shared__ float Xs[16][72];
  __shared__ float Ws[16][72];

  const int t  = threadIdx.x;
  const int tx = t & 15, ty = t >> 4;
  const int tile_n = blockIdx.x * 64;
  const int tile_m = blockIdx.y * 64;

  const int lr = t >> 2;
  const int lk = (t & 3) * 4;
  const int wk = t >> 4;
  const int wn = (t & 15) * 4;

  float acc[4][4] = {};

  for (int k0 = 0; k0 < 512; k0 += 16) {
    float4 xv = *(const float4*)&X[(size_t)(tile_m + lr) * 512 + k0 + lk];
    Xs[lk+0][lr] = xv.x; Xs[lk+1][lr] = xv.y; Xs[lk+2][lr] = xv.z; Xs[lk+3][lr] = xv.w;
    float4 wv = *(const float4*)&Wo[(size_t)(k0 + wk) * 512 + tile_n + wn];
    *(float4*)&Ws[wk][wn] = wv;
    __syncthreads();
    #pragma unroll
    for (int kk = 0; kk < 16; ++kk) {
      float4 af = *(const float4*)&Xs[kk][ty*4];
      float4 bf = *(const float4*)&Ws[kk][tx*4];
      float a[4] = {af.x, af.y, af.z, af.w};
      float b[4] = {bf.x, bf.y, bf.z, bf.w};
      #pragma unroll
      for (int i = 0; i < 4; ++i)
        #pragma unroll
        for (int j = 0; j < 4; ++j)
          acc[i][j] = fmaf(a[i], b[j], acc[i][j]);
    }
    __syncthreads();
  }

  #pragma unroll
  for (int i = 0; i < 4; ++i) {
    size_t r = tile_m + ty * 4 + i;
    size_t c = tile_n + tx * 4;
    float4 rr = *(const float4*)&resid[r * 512 + c];
    float4 o = make_float4(acc[i][0] + rr.x, acc[i][1] + rr.y,
                           acc[i][2] + rr.z, acc[i][3] + rr.w);
    *(float4*)&Y[r * 512 + c] = o;
  }
}

// ---------------------------------------------------------------------------
// Kernel 4: in-place LayerNorm over last dim (512), one wave per row.
// ---------------------------------------------------------------------------
__global__ __launch_bounds__(256) void ln_kernel(
    float* __restrict__ io, const float* __restrict__ gamma, const float* __restrict__ beta)
{
  const int wid  = threadIdx.x >> 6;
  const int lane = threadIdx.x & 63;
  const size_t row = (size_t)blockIdx.x * 4 + wid;
  const size_t base = row * 512 + lane * 8;

  float4 x0 = *(const float4*)&io[base];
  float4 x1 = *(const float4*)&io[base + 4];
  float xs[8] = {x0.x, x0.y, x0.z, x0.w, x1.x, x1.y, x1.z, x1.w};

  float s = 0.f, s2 = 0.f;
  #pragma unroll
  for (int i = 0; i < 8; ++i) { s += xs[i]; s2 = fmaf(xs[i], xs[i], s2); }
  #pragma unroll
  for (int m = 1; m < 64; m <<= 1) {
    s  += __shfl_xor(s, m);
    s2 += __shfl_xor(s2, m);
  }
  float mu  = s * (1.f / 512.f);
  float var = s2 * (1.f / 512.f) - mu * mu;
  float rs  = rsqrtf(var + 1e-6f);

  float4 g0 = *(const float4*)&gamma[lane * 8];
  float4 g1 = *(const float4*)&gamma[lane * 8 + 4];
  float4 b0 = *(const float4*)&beta[lane * 8];
  float4 b1 = *(const float4*)&beta[lane * 8 + 4];
  float gs[8] = {g0.x, g0.y, g0.z, g0.w, g1.x, g1.y, g1.z, g1.w};
  float bs[8] = {b0.x, b0.y, b0.z, b0.w, b1.x, b1.y, b1.z, b1.w};

  float ys[8];
  #pragma unroll
  for (int i = 0; i < 8; ++i) ys[i] = (xs[i] - mu) * rs * gs[i] + bs[i];
  *(float4*)&io[base]     = make_float4(ys[0], ys[1], ys[2], ys[3]);
  *(float4*)&io[base + 4] = make_float4(ys[4], ys[5], ys[6], ys[7]);
}

// ---------------------------------------------------------------------------
extern "C" void kernel_launch(void* const* d_in, const int* in_sizes, int n_in,
                              void* d_out, int out_size, void* d_ws, size_t ws_size,
                              hipStream_t stream)
{
  const float* q     = (const float*)d_in[0];
  const float* k     = (const float*)d_in[1];
  const float* v     = (const float*)d_in[2];
  const int*  smask  = (const int*)d_in[3];
  const float* Wq    = (const float*)d_in[4];
  const float* Wk    = (const float*)d_in[5];
  const float* Wv    = (const float*)d_in[6];
  const float* Wo    = (const float*)d_in[7];
  const float* gamma = (const float*)d_in[8];
  const float* beta  = (const float*)d_in[9];

  float* out  = (float*)d_out;
  float* attn = out + (size_t)B_ * S_ * D_;     // 4,194,304 offset

  float* ws = (float*)d_ws;
  float* qh = ws;                      // [B,H,S,64]  4M floats
  float* kh = ws + 4194304;
  float* vh = ws + 8388608;
  float* oh = ws + 12582912;           // [B*S, 512]  4M floats

  qkv_gemm<<<dim3(8, 128, 3), 256, 0, stream>>>(q, k, v, Wq, Wk, Wv, qh, kh, vh);
  attn_kernel<<<dim3(32, 32), 256, 0, stream>>>(qh, kh, vh, smask, attn, oh);
  out_gemm<<<dim3(8, 128), 256, 0, stream>>>(oh, Wo, q, out);
  ln_kernel<<<2048, 256, 0, stream>>>(out, gamma, beta);
}

// Round 2
// 804.326 us; speedup vs baseline: 1.9541x; 1.9541x over previous
//
#include <hip/hip_runtime.h>
#include <math.h>

#define B_ 4
#define S_ 2048
#define D_ 512
#define H_ 8
#define NEG_FILL (-1e-9f)

typedef __attribute__((ext_vector_type(8))) short bf16x8;
typedef __attribute__((ext_vector_type(4))) float f32x4;

#define MFMA16(A, Bm, C) __builtin_amdgcn_mfma_f32_16x16x32_bf16((A), (Bm), (C), 0, 0, 0)

__device__ __forceinline__ short f2b(float f) {
  union { float f; unsigned u; } x;
  x.f = f;
  unsigned r = x.u + 0x7fffu + ((x.u >> 16) & 1u);
  return (short)(r >> 16);
}

// ---------------------------------------------------------------------------
// prep: W[512x512] fp32 (k-major) -> Wt[n][k] bf16 (transposed), z picks matrix
// ---------------------------------------------------------------------------
__global__ __launch_bounds__(256) void prep_wt(
    const float* __restrict__ Wq, const float* __restrict__ Wk,
    const float* __restrict__ Wv, const float* __restrict__ Wo,
    short* __restrict__ Wqt, short* __restrict__ Wkt,
    short* __restrict__ Wvt, short* __restrict__ Wot)
{
  const float* W; short* Wt;
  switch (blockIdx.z) {
    case 0: W = Wq; Wt = Wqt; break;
    case 1: W = Wk; Wt = Wkt; break;
    case 2: W = Wv; Wt = Wvt; break;
    default: W = Wo; Wt = Wot; break;
  }
  __shared__ float Ws[64 * 68];
  const int t = threadIdx.x;
  const int n0 = blockIdx.x * 64, k0 = blockIdx.y * 64;

  #pragma unroll
  for (int rep = 0; rep < 4; ++rep) {
    int e4 = rep * 256 + t;           // float4 units
    int r = e4 >> 4, c0 = (e4 & 15) * 4;
    *(float4*)&Ws[r * 68 + c0] = *(const float4*)&W[(size_t)(k0 + r) * 512 + n0 + c0];
  }
  __syncthreads();

  int rn = t >> 2;                    // out row (n)
  int kb = (t & 3) * 16;              // out col base (k)
  union { short s[8]; int4 v; } pk;
  #pragma unroll
  for (int half = 0; half < 2; ++half) {
    #pragma unroll
    for (int i = 0; i < 8; ++i)
      pk.s[i] = f2b(Ws[(kb + half * 8 + i) * 68 + rn]);
    *(int4*)&Wt[(size_t)(n0 + rn) * 512 + k0 + kb + half * 8] = pk.v;
  }
}

// ---------------------------------------------------------------------------
// QKV projection, MFMA bf16. X[8192x512] fp32, Wt[n][k] bf16.
// z=0 -> qh[bh][s][64], z=1 -> kh[bh][s][64], z=2 -> vt[bh][d][2048]
// ---------------------------------------------------------------------------
__global__ __launch_bounds__(256) void qkv_mfma(
    const float* __restrict__ q, const float* __restrict__ k, const float* __restrict__ v,
    const short* __restrict__ Wqt, const short* __restrict__ Wkt, const short* __restrict__ Wvt,
    short* __restrict__ qh, short* __restrict__ kh, short* __restrict__ vt)
{
  const int z = blockIdx.z;
  const float* X = (z == 0) ? q : (z == 1) ? k : v;
  const short* Wt = (z == 0) ? Wqt : (z == 1) ? Wkt : Wvt;

  __shared__ short Xs[64 * 72];
  __shared__ short Wsh[64 * 72];

  const int t = threadIdx.x;
  const int wave = t >> 6, lane = t & 63, quad = lane >> 4, l15 = lane & 15;
  const int tile_n = blockIdx.x * 64;
  const int tile_m = blockIdx.y * 64;

  f32x4 acc[4];
  #pragma unroll
  for (int nt = 0; nt < 4; ++nt) acc[nt] = (f32x4){0.f, 0.f, 0.f, 0.f};

  for (int k0 = 0; k0 < 512; k0 += 64) {
    __syncthreads();
    #pragma unroll
    for (int rep = 0; rep < 4; ++rep) {
      int e4 = rep * 256 + t;
      int row = e4 >> 4, c0 = (e4 & 15) * 4;
      float4 xv = *(const float4*)&X[(size_t)(tile_m + row) * 512 + k0 + c0];
      *(short4*)&Xs[row * 72 + c0] =
          make_short4(f2b(xv.x), f2b(xv.y), f2b(xv.z), f2b(xv.w));
    }
    #pragma unroll
    for (int rep = 0; rep < 2; ++rep) {
      int e = rep * 256 + t;
      int row = e >> 3, c0 = (e & 7) * 8;
      *(int4*)&Wsh[row * 72 + c0] = *(const int4*)&Wt[(size_t)(tile_n + row) * 512 + k0 + c0];
    }
    __syncthreads();
    #pragma unroll
    for (int ks = 0; ks < 2; ++ks) {
      bf16x8 af = *(bf16x8*)&Xs[(wave * 16 + l15) * 72 + ks * 32 + quad * 8];
      #pragma unroll
      for (int nt = 0; nt < 4; ++nt) {
        bf16x8 bfr = *(bf16x8*)&Wsh[(nt * 16 + l15) * 72 + ks * 32 + quad * 8];
        acc[nt] = MFMA16(af, bfr, acc[nt]);
      }
    }
  }

  const int h = tile_n >> 6;
  if (z < 2) {
    short* Y = (z == 0) ? qh : kh;
    #pragma unroll
    for (int nt = 0; nt < 4; ++nt) {
      int d = nt * 16 + l15;
      #pragma unroll
      for (int r = 0; r < 4; ++r) {
        int row = tile_m + wave * 16 + quad * 4 + r;
        int b = row >> 11, s = row & (S_ - 1);
        Y[(((size_t)(b * H_ + h)) * S_ + s) * 64 + d] = f2b(acc[nt][r]);
      }
    }
  } else {
    int row0 = tile_m + wave * 16 + quad * 4;
    int b = row0 >> 11, s0 = row0 & (S_ - 1);
    #pragma unroll
    for (int nt = 0; nt < 4; ++nt) {
      int d = nt * 16 + l15;
      short4 pk = make_short4(f2b(acc[nt][0]), f2b(acc[nt][1]),
                              f2b(acc[nt][2]), f2b(acc[nt][3]));
      *(short4*)&vt[(((size_t)(b * H_ + h)) * 64 + d) * S_ + s0] = pk;
    }
  }
}

// ---------------------------------------------------------------------------
// Fused attention, MFMA bf16. Block = (64 q-rows, one bh). Two passes over K.
// qh/kh: [bh][s][64] bf16 ; vt: [bh][d][2048] bf16.
// Writes attn fp32 [bh][s][2048] and ohb bf16 [b*s][512].
// ---------------------------------------------------------------------------
__global__ __launch_bounds__(256) void attn_mfma(
    const short* __restrict__ qh, const short* __restrict__ kh,
    const short* __restrict__ vt, const int* __restrict__ src_mask,
    float* __restrict__ attn_out, short* __restrict__ ohb)
{
  const int t = threadIdx.x;
  const int wave = t >> 6, lane = t & 63, quad = lane >> 4, l15 = lane & 15;
  const int q0 = blockIdx.x * 64;
  const int bh = blockIdx.y, b = bh >> 3, h = bh & 7;

  __shared__ short Ks[64 * 72];
  __shared__ short Vs[64 * 72];
  __shared__ short Ps[64 * 72];     // Q staging at init, P tile in pass B
  __shared__ int smq[64], smk[64];

  // ---- stage Q tile (into Ps scratch), masks ----
  #pragma unroll
  for (int rep = 0; rep < 2; ++rep) {
    int e = rep * 256 + t;
    int row = e >> 3, c0 = (e & 7) * 8;
    *(int4*)&Ps[row * 72 + c0] =
        *(const int4*)&qh[((size_t)bh * S_ + q0 + row) * 64 + c0];
  }
  if (t < 64) smq[t] = src_mask[b * S_ + q0 + t];
  __syncthreads();

  bf16x8 qf[2];
  #pragma unroll
  for (int ks = 0; ks < 2; ++ks)
    qf[ks] = *(bf16x8*)&Ps[(wave * 16 + l15) * 72 + ks * 32 + quad * 8];

  int rloc[4], mqr[4], qir[4];
  #pragma unroll
  for (int r = 0; r < 4; ++r) {
    rloc[r] = wave * 16 + quad * 4 + r;
    mqr[r] = smq[rloc[r]];
    qir[r] = q0 + rloc[r];
  }

  // ---------------- Pass A: exp-sums (no max subtraction needed) ----------
  float rs[4] = {0.f, 0.f, 0.f, 0.f};
  for (int kt0 = 0; kt0 < S_; kt0 += 64) {
    __syncthreads();
    #pragma unroll
    for (int rep = 0; rep < 2; ++rep) {
      int e = rep * 256 + t;
      int row = e >> 3, c0 = (e & 7) * 8;
      *(int4*)&Ks[row * 72 + c0] =
          *(const int4*)&kh[((size_t)bh * S_ + kt0 + row) * 64 + c0];
    }
    if (t < 64) smk[t] = src_mask[b * S_ + kt0 + t];
    __syncthreads();

    #pragma unroll
    for (int nt = 0; nt < 4; ++nt) {
      f32x4 c = (f32x4){0.f, 0.f, 0.f, 0.f};
      #pragma unroll
      for (int ks = 0; ks < 2; ++ks) {
        bf16x8 kf = *(bf16x8*)&Ks[(nt * 16 + l15) * 72 + ks * 32 + quad * 8];
        c = MFMA16(qf[ks], kf, c);
      }
      int mk = smk[nt * 16 + l15];
      int kj = kt0 + nt * 16 + l15;
      #pragma unroll
      for (int r = 0; r < 4; ++r) {
        float ss = c[r] * 0.125f;
        bool keep = (mqr[r] & mk) || (qir[r] == kj);
        ss = keep ? ss : NEG_FILL;
        rs[r] += __expf(ss);
      }
    }
  }
  // reduce across the 16 lanes holding one row's columns; keep inverse
  #pragma unroll
  for (int r = 0; r < 4; ++r) {
    float vsum = rs[r];
    vsum += __shfl_xor(vsum, 1);
    vsum += __shfl_xor(vsum, 2);
    vsum += __shfl_xor(vsum, 4);
    vsum += __shfl_xor(vsum, 8);
    rs[r] = 1.f / vsum;
  }

  // ---------------- Pass B: attn write + PV ----------------
  f32x4 oacc[4];
  #pragma unroll
  for (int dt = 0; dt < 4; ++dt) oacc[dt] = (f32x4){0.f, 0.f, 0.f, 0.f};

  for (int kt0 = 0; kt0 < S_; kt0 += 64) {
    __syncthreads();
    #pragma unroll
    for (int rep = 0; rep < 2; ++rep) {
      int e = rep * 256 + t;
      int row = e >> 3, c0 = (e & 7) * 8;
      *(int4*)&Ks[row * 72 + c0] =
          *(const int4*)&kh[((size_t)bh * S_ + kt0 + row) * 64 + c0];
      *(int4*)&Vs[row * 72 + c0] =
          *(const int4*)&vt[((size_t)bh * 64 + row) * S_ + kt0 + c0];
    }
    if (t < 64) smk[t] = src_mask[b * S_ + kt0 + t];
    __syncthreads();

    #pragma unroll
    for (int nt = 0; nt < 4; ++nt) {
      f32x4 c = (f32x4){0.f, 0.f, 0.f, 0.f};
      #pragma unroll
      for (int ks = 0; ks < 2; ++ks) {
        bf16x8 kf = *(bf16x8*)&Ks[(nt * 16 + l15) * 72 + ks * 32 + quad * 8];
        c = MFMA16(qf[ks], kf, c);
      }
      int mk = smk[nt * 16 + l15];
      int kj = kt0 + nt * 16 + l15;
      #pragma unroll
      for (int r = 0; r < 4; ++r) {
        float ss = c[r] * 0.125f;
        bool keep = (mqr[r] & mk) || (qir[r] == kj);
        ss = keep ? ss : NEG_FILL;
        float p = __expf(ss) * rs[r];
        attn_out[((size_t)bh * S_ + q0 + rloc[r]) * S_ + kj] = p;
        Ps[rloc[r] * 72 + nt * 16 + l15] = f2b(p);
      }
    }
    __syncthreads();

    bf16x8 pf[2];
    #pragma unroll
    for (int ks = 0; ks < 2; ++ks)
      pf[ks] = *(bf16x8*)&Ps[(wave * 16 + l15) * 72 + ks * 32 + quad * 8];
    #pragma unroll
    for (int dt = 0; dt < 4; ++dt) {
      #pragma unroll
      for (int ks = 0; ks < 2; ++ks) {
        bf16x8 vf = *(bf16x8*)&Vs[(dt * 16 + l15) * 72 + ks * 32 + quad * 8];
        oacc[dt] = MFMA16(pf[ks], vf, oacc[dt]);
      }
    }
  }

  // ---- write O tile (bf16) ----
  #pragma unroll
  for (int dt = 0; dt < 4; ++dt) {
    int d = h * 64 + dt * 16 + l15;
    #pragma unroll
    for (int r = 0; r < 4; ++r)
      ohb[((size_t)b * S_ + q0 + rloc[r]) * 512 + d] = f2b(oacc[dt][r]);
  }
}

// ---------------------------------------------------------------------------
// out = ohb @ Wo + residual(q), MFMA bf16, fp32 out.
// ---------------------------------------------------------------------------
__global__ __launch_bounds__(256) void out_mfma(
    const short* __restrict__ ohb, const short* __restrict__ Wot,
    const float* __restrict__ resid, float* __restrict__ out)
{
  __shared__ short Xs[64 * 72];
  __shared__ short Wsh[64 * 72];

  const int t = threadIdx.x;
  const int wave = t >> 6, lane = t & 63, quad = lane >> 4, l15 = lane & 15;
  const int tile_n = blockIdx.x * 64;
  const int tile_m = blockIdx.y * 64;

  f32x4 acc[4];
  #pragma unroll
  for (int nt = 0; nt < 4; ++nt) acc[nt] = (f32x4){0.f, 0.f, 0.f, 0.f};

  for (int k0 = 0; k0 < 512; k0 += 64) {
    __syncthreads();
    #pragma unroll
    for (int rep = 0; rep < 2; ++rep) {
      int e = rep * 256 + t;
      int row = e >> 3, c0 = (e & 7) * 8;
      *(int4*)&Xs[row * 72 + c0] = *(const int4*)&ohb[(size_t)(tile_m + row) * 512 + k0 + c0];
      *(int4*)&Wsh[row * 72 + c0] = *(const int4*)&Wot[(size_t)(tile_n + row) * 512 + k0 + c0];
    }
    __syncthreads();
    #pragma unroll
    for (int ks = 0; ks < 2; ++ks) {
      bf16x8 af = *(bf16x8*)&Xs[(wave * 16 + l15) * 72 + ks * 32 + quad * 8];
      #pragma unroll
      for (int nt = 0; nt < 4; ++nt) {
        bf16x8 bfr = *(bf16x8*)&Wsh[(nt * 16 + l15) * 72 + ks * 32 + quad * 8];
        acc[nt] = MFMA16(af, bfr, acc[nt]);
      }
    }
  }

  #pragma unroll
  for (int nt = 0; nt < 4; ++nt) {
    int c = tile_n + nt * 16 + l15;
    #pragma unroll
    for (int r = 0; r < 4; ++r) {
      size_t row = tile_m + wave * 16 + quad * 4 + r;
      out[row * 512 + c] = acc[nt][r] + resid[row * 512 + c];
    }
  }
}

// ---------------------------------------------------------------------------
// LayerNorm over last dim (512), one wave per row, in place.
// ---------------------------------------------------------------------------
__global__ __launch_bounds__(256) void ln_kernel(
    float* __restrict__ io, const float* __restrict__ gamma, const float* __restrict__ beta)
{
  const int wid  = threadIdx.x >> 6;
  const int lane = threadIdx.x & 63;
  const size_t row = (size_t)blockIdx.x * 4 + wid;
  const size_t base = row * 512 + lane * 8;

  float4 x0 = *(const float4*)&io[base];
  float4 x1 = *(const float4*)&io[base + 4];
  float xs[8] = {x0.x, x0.y, x0.z, x0.w, x1.x, x1.y, x1.z, x1.w};

  float s = 0.f, s2 = 0.f;
  #pragma unroll
  for (int i = 0; i < 8; ++i) { s += xs[i]; s2 = fmaf(xs[i], xs[i], s2); }
  #pragma unroll
  for (int m = 1; m < 64; m <<= 1) {
    s  += __shfl_xor(s, m);
    s2 += __shfl_xor(s2, m);
  }
  float mu  = s * (1.f / 512.f);
  float var = s2 * (1.f / 512.f) - mu * mu;
  float rsq = rsqrtf(var + 1e-6f);

  float4 g0 = *(const float4*)&gamma[lane * 8];
  float4 g1 = *(const float4*)&gamma[lane * 8 + 4];
  float4 b0 = *(const float4*)&beta[lane * 8];
  float4 b1 = *(const float4*)&beta[lane * 8 + 4];
  float gs[8] = {g0.x, g0.y, g0.z, g0.w, g1.x, g1.y, g1.z, g1.w};
  float bs[8] = {b0.x, b0.y, b0.z, b0.w, b1.x, b1.y, b1.z, b1.w};

  float ys[8];
  #pragma unroll
  for (int i = 0; i < 8; ++i) ys[i] = (xs[i] - mu) * rsq * gs[i] + bs[i];
  *(float4*)&io[base]     = make_float4(ys[0], ys[1], ys[2], ys[3]);
  *(float4*)&io[base + 4] = make_float4(ys[4], ys[5], ys[6], ys[7]);
}

// ---------------------------------------------------------------------------
extern "C" void kernel_launch(void* const* d_in, const int* in_sizes, int n_in,
                              void* d_out, int out_size, void* d_ws, size_t ws_size,
                              hipStream_t stream)
{
  const float* q     = (const float*)d_in[0];
  const float* k     = (const float*)d_in[1];
  const float* v     = (const float*)d_in[2];
  const int*  smask  = (const int*)d_in[3];
  const float* Wq    = (const float*)d_in[4];
  const float* Wk    = (const float*)d_in[5];
  const float* Wv    = (const float*)d_in[6];
  const float* Wo    = (const float*)d_in[7];
  const float* gamma = (const float*)d_in[8];
  const float* beta  = (const float*)d_in[9];

  float* out  = (float*)d_out;
  float* attn = out + (size_t)B_ * S_ * D_;

  short* wsS = (short*)d_ws;
  short* qh  = wsS;                    // [32 bh][2048][64]
  short* kh  = qh + 4194304;
  short* vt  = kh + 4194304;           // [32 bh][64][2048]
  short* ohb = vt + 4194304;           // [8192][512]
  short* Wqt = ohb + 4194304;          // [512][512] each
  short* Wkt = Wqt + 262144;
  short* Wvt = Wkt + 262144;
  short* Wot = Wvt + 262144;

  prep_wt<<<dim3(8, 8, 4), 256, 0, stream>>>(Wq, Wk, Wv, Wo, Wqt, Wkt, Wvt, Wot);
  qkv_mfma<<<dim3(8, 128, 3), 256, 0, stream>>>(q, k, v, Wqt, Wkt, Wvt, qh, kh, vt);
  attn_mfma<<<dim3(32, 32), 256, 0, stream>>>(qh, kh, vt, smask, attn, ohb);
  out_mfma<<<dim3(8, 128), 256, 0, stream>>>(ohb, Wot, q, out);
  ln_kernel<<<2048, 256, 0, stream>>>(out, gamma, beta);
}